// Round 3
// 100.693 us; speedup vs baseline: 1.0010x; 1.0010x over previous
//
#include <hip/hip_runtime.h>
#include <hip/hip_fp16.h>

// GEMM view: Out[(b,d), c] = sum_k A[(b,d),k] * Bk[k,c]
//   row = b*32 + d (M=131072), k = i*32+j (K=1024), col = c (N=64)
// A[(b,d), i*32+j] = x[b,i,d] * y[b,j,d]  — rank-1 in (i,j), built in regs.
// R6: counted-vmcnt pipeline (T3+T4) replacing the 8x __syncthreads drain:
//  - x is streamed per-chunk (x[b,i,:] only used in k-step i) via
//    global_load_lds as raw f32 (4 KB/chunk, 1 call/thread); dup->f16 with one
//    cvt_pkrtz in-loop (identical numerics to the old staged dup path).
//  - 3-slot LDS ring {B 16KB + x 4KB}/chunk = 60 KB total, 2 blocks/CU.
//  - per phase: s_waitcnt vmcnt(5) (vmcnt(0) only on last chunk) + raw
//    s_barrier + sched_barrier(0); chunk i+2 issued AFTER the barrier (the
//    barrier is what frees slot (i-1)%3 — each wave's own 5-call FIFO +
//    barrier makes the whole chunk visible, same as the 8-phase template).
//  - T5 setprio(1) around the MFMA cluster (phase-split regime).
// 512 blocks x 256 thr, 8 b/block, wave = 2 b x full C.

typedef __attribute__((ext_vector_type(8))) _Float16 half8;   // MFMA operand
typedef __attribute__((ext_vector_type(2))) __fp16 fp16x2;    // cvt_pkrtz/pk_mul
typedef __attribute__((ext_vector_type(4))) float f32x4;
typedef __attribute__((ext_vector_type(8))) short short8;

__device__ __forceinline__ unsigned int dup_h(float f) {
    union { fp16x2 h; unsigned int u; } w;
    w.h = __builtin_amdgcn_cvt_pkrtz(f, f);
    return w.u;
}
__device__ __forceinline__ fp16x2 pk2(float a, float b) {
    return __builtin_amdgcn_cvt_pkrtz(a, b);
}

// kswz f16 frag order: g = (s*4+nt)*64 + lane,
// kswz[g*8+t] = f16(kernel[c = nt*16+(lane&15)][s][(lane>>4)*8 + t])
__global__ __launch_bounds__(256) void kswz_kernel(const float* __restrict__ kern,
                                                   unsigned short* __restrict__ kswz) {
    int idx  = blockIdx.x * 256 + threadIdx.x;  // 8192
    int lane = idx & 63;
    int nt   = (idx >> 6) & 3;
    int s    = idx >> 8;
    int c    = nt * 16 + (lane & 15);
    int jb   = (lane >> 4) * 8;
    const float* src = kern + c * 1024 + s * 32 + jb;
    union { half8 h; short8 s8; } v;
#pragma unroll
    for (int t = 0; t < 8; ++t) v.h[t] = (_Float16)src[t];  // RNE
    *(short8*)(kswz + (size_t)idx * 8) = v.s8;
}

__device__ __forceinline__ void gld_lds16(const void* g, void* l) {
    __builtin_amdgcn_global_load_lds(
        (const __attribute__((address_space(1))) unsigned int*)g,
        (__attribute__((address_space(3))) unsigned int*)l, 16, 0, 0);
}

__global__ __launch_bounds__(256, 2) void cin_main(const float* __restrict__ x,
                                                   const float* __restrict__ y,
                                                   const unsigned short* __restrict__ kswz,
                                                   float* __restrict__ out_mat,
                                                   float* __restrict__ out_fin) {
    __shared__ __align__(16) unsigned short kb[3][8192];  // 48 KB: B ring (16 KB/chunk)
    __shared__ __align__(16) float xb[3][1024];           // 12 KB: x ring (4 KB/chunk)

    const int tid  = threadIdx.x;
    const int wave = tid >> 6;        // 0..3
    const int lane = tid & 63;
    const int quad = lane >> 4;
    const int n16  = lane & 15;
    const int b_blk = blockIdx.x * 8;
    const int cq0   = blockIdx.x & 7;

    // per-thread x-DMA source decomposition: elem idx = tid*4 = bb*128+ii*32+d4*4
    const int xbb = tid >> 5;         // b within block 0..7
    const int xii = (tid >> 3) & 3;   // i within chunk 0..3
    const int xd4 = tid & 7;          // float4 within row

    // ---- issue one chunk's DMA: B 4 calls + x 1 call per thread ----
    auto issue_chunk = [&](int ci, int slot) {
#pragma unroll
        for (int r = 0; r < 4; ++r)
            gld_lds16(kswz + (size_t)ci * 8192 + (r * 256 + tid) * 8,
                      &kb[slot][r * 2048 + wave * 512]);
        gld_lds16(x + (size_t)(b_blk + xbb) * 1024 + ci * 128 + xii * 32 + xd4 * 4,
                  &xb[slot][wave * 256]);
    };

    // prologue: chunks cq0, cq0+1 into slots 0,1 (DMA runs under the y-load)
    issue_chunk(cq0, 0);
    issue_chunk((cq0 + 1) & 7, 1);

    // ---- y fragments as packed pairs: yv2[mt][p] = {y[b,j=q8+2p,d], y[b,j=q8+2p+1,d]} ----
    const int b0 = b_blk + wave * 2;  // wave owns b0..b0+1
    fp16x2 yv2[4][4];
#pragma unroll
    for (int mt = 0; mt < 4; ++mt) {
        const int b = b0 + (mt >> 1);
        const int d = n16 + 16 * (mt & 1);
        const float* yp = y + (size_t)b * 1024 + (quad * 8) * 32 + d;
#pragma unroll
        for (int p = 0; p < 4; ++p)
            yv2[mt][p] = pk2(yp[(2 * p) * 32], yp[(2 * p + 1) * 32]);
    }

    f32x4 acc[4][4];
#pragma unroll
    for (int mt = 0; mt < 4; ++mt)
#pragma unroll
        for (int nt = 0; nt < 4; ++nt) acc[mt][nt] = (f32x4){0.f, 0.f, 0.f, 0.f};

#pragma unroll
    for (int p8 = 0; p8 < 8; ++p8) {
        // chunk p8 ready = this wave's own 5 calls retired (all but the last 5
        // outstanding are retired -> everything through chunk p8 landed);
        // barrier makes all 4 waves' segments visible AND frees slot (p8-1)%3.
        if (p8 < 7) asm volatile("s_waitcnt vmcnt(5)" ::: "memory");
        else        asm volatile("s_waitcnt vmcnt(0)" ::: "memory");
        __builtin_amdgcn_s_barrier();
        __builtin_amdgcn_sched_barrier(0);   // rule 18: no hoist above the wait

        if (p8 < 6) issue_chunk((cq0 + p8 + 2) & 7, (p8 + 2) % 3);

        const unsigned short* kbase = &kb[p8 % 3][0];
        const float*          xbase = &xb[p8 % 3][0];

        __builtin_amdgcn_s_setprio(1);
#pragma unroll
        for (int k = 0; k < 4; ++k) {
            half8 bf[4];
#pragma unroll
            for (int nt = 0; nt < 4; ++nt)
                bf[nt] = *(const half8*)(kbase + ((k * 4 + nt) * 64 + lane) * 8);
#pragma unroll
            for (int mt = 0; mt < 4; ++mt) {
                float xf = xbase[(wave * 2 + (mt >> 1)) * 128 + k * 32 + n16 + 16 * (mt & 1)];
                union { unsigned int u; fp16x2 h; } xv;
                xv.u = dup_h(xf);
                union { half8 h8; fp16x2 h2[4]; } af;
#pragma unroll
                for (int p = 0; p < 4; ++p) af.h2[p] = xv.h * yv2[mt][p];  // v_pk_mul_f16
#pragma unroll
                for (int nt = 0; nt < 4; ++nt)
                    acc[mt][nt] = __builtin_amdgcn_mfma_f32_16x16x32_f16(
                        af.h8, bf[nt], acc[mt][nt], 0, 0, 0);
            }
        }
        __builtin_amdgcn_s_setprio(0);
    }

    // ---- epilogue: output_mat[b][c][d], d = 16*(mt&1) + quad*4 + t ----
#pragma unroll
    for (int mt = 0; mt < 4; ++mt) {
        const int b = b0 + (mt >> 1);
        const int dbase = 16 * (mt & 1) + quad * 4;
#pragma unroll
        for (int nt = 0; nt < 4; ++nt) {
            const int c = nt * 16 + n16;
            *(f32x4*)(out_mat + (size_t)b * 2048 + c * 32 + dbase) = acc[mt][nt];
        }
    }

    // ---- final_output[b][c] = sum_d output_mat[b][c][d] ----
#pragma unroll
    for (int a = 0; a < 2; ++a) {
        const int b = b0 + a;
#pragma unroll
        for (int nt = 0; nt < 4; ++nt) {
            float f = 0.f;
#pragma unroll
            for (int t = 0; t < 4; ++t) f += acc[2 * a][nt][t] + acc[2 * a + 1][nt][t];
            f += __shfl_xor(f, 16);
            f += __shfl_xor(f, 32);
            if (lane < 16) out_fin[(size_t)b * 64 + nt * 16 + n16] = f;
        }
    }
}

extern "C" void kernel_launch(void* const* d_in, const int* in_sizes, int n_in,
                              void* d_out, int out_size, void* d_ws, size_t ws_size,
                              hipStream_t stream) {
    const float* x    = (const float*)d_in[0];   // [4096,32,32]
    const float* y    = (const float*)d_in[1];   // [4096,32,32]
    const float* kern = (const float*)d_in[2];   // [64,32,32]
    float* out_mat = (float*)d_out;                      // [4096,64,32]
    float* out_fin = (float*)d_out + 4096 * 64 * 32;     // [4096,64]
    unsigned short* kswz = (unsigned short*)d_ws;        // 65536 f16 = 128 KB

    kswz_kernel<<<32, 256, 0, stream>>>(kern, kswz);
    cin_main<<<512, 256, 0, stream>>>(x, y, kswz, out_mat, out_fin);
}